// Round 7
// baseline (98.680 us; speedup 1.0000x reference)
//
#include <hip/hip_runtime.h>

#define NALL 1024
#define NH   512
#define NCOL 8
#define ROWS_PER_BLOCK 64
#define THREADS 256
#define CHUNKS 16
#define SAMPLES 2
#define BR 4                         // rows per batch (slot)
#define NSLOT (SAMPLES * ROWS_PER_BLOCK / BR)   // 32

typedef float f32x4 __attribute__((ext_vector_type(4)));

__device__ __forceinline__ f32x4 nt_load(const float* p) {
    return __builtin_nontemporal_load(reinterpret_cast<const f32x4*>(p));
}

// Fused, barrier-free kernel. Block = (sample pair, 64-row chunk), 4 waves.
// Each wave: redundant per-wave column-norm reduce (L2-resident u,v, shfl
// butterfly -> no barriers), private wl copy in LDS, right-fragment in regs.
// x is streamed in 4-row double-buffered register slots (slot i+1 always in
// flight while slot i computes) -> no inter-batch vmcnt drain.
// out[b][q*8+c], q = ih + 2*jh.
__global__ __launch_bounds__(THREADS, 4) void jxy_kernel(
    const float* __restrict__ x, const float* __restrict__ u,
    const float* __restrict__ v, float* __restrict__ out) {
    const int bid   = blockIdx.x;
    const int pair  = bid >> 4;
    const int chunk = bid & (CHUNKS - 1);
    const int r0    = chunk * ROWS_PER_BLOCK;
    const int ih    = (r0 >= NH) ? 1 : 0;
    const int rloc  = r0 - ih * NH;

    const int tid  = threadIdx.x;
    const int wave = tid >> 6;
    const int lane = tid & 63;
    const int jbase = wave * 256 + lane * 4;
    const int jh    = (jbase >= NH) ? 1 : 0;
    const int jloc  = jbase - jh * NH;

    const float* xrow0 = x + ((size_t)(pair * SAMPLES) * NALL + r0) * NALL + jbase;
    const float* xrow1 = xrow0 + (size_t)NALL * NALL;

    f32x4 buf[2][BR];

    // ---- prefetch slot 0 BEFORE the prologue (HBM latency covers norms) ----
#pragma unroll
    for (int k = 0; k < BR; ++k)
        buf[0][k] = nt_load(xrow0 + (size_t)k * NALL);

    // ---- barrier-free prologue: per-wave joint column norms ----
    float nrm[NCOL];
#pragma unroll
    for (int c = 0; c < NCOL; ++c) nrm[c] = 0.f;
    for (int r = lane; r < NH; r += 64) {
        const f32x4* up = reinterpret_cast<const f32x4*>(u + r * NCOL);
        const f32x4* vp = reinterpret_cast<const f32x4*>(v + r * NCOL);
        f32x4 a0 = up[0], a1 = up[1], b0 = vp[0], b1 = vp[1];
        nrm[0] = fmaf(a0.x, a0.x, fmaf(b0.x, b0.x, nrm[0]));
        nrm[1] = fmaf(a0.y, a0.y, fmaf(b0.y, b0.y, nrm[1]));
        nrm[2] = fmaf(a0.z, a0.z, fmaf(b0.z, b0.z, nrm[2]));
        nrm[3] = fmaf(a0.w, a0.w, fmaf(b0.w, b0.w, nrm[3]));
        nrm[4] = fmaf(a1.x, a1.x, fmaf(b1.x, b1.x, nrm[4]));
        nrm[5] = fmaf(a1.y, a1.y, fmaf(b1.y, b1.y, nrm[5]));
        nrm[6] = fmaf(a1.z, a1.z, fmaf(b1.z, b1.z, nrm[6]));
        nrm[7] = fmaf(a1.w, a1.w, fmaf(b1.w, b1.w, nrm[7]));
    }
#pragma unroll
    for (int c = 0; c < NCOL; ++c) {
#pragma unroll
        for (int off = 32; off >= 1; off >>= 1)
            nrm[c] += __shfl_xor(nrm[c], off, 64);
    }
    float inv[NCOL];
#pragma unroll
    for (int c = 0; c < NCOL; ++c) inv[c] = 1.0f / sqrtf(nrm[c]);

    // ---- per-wave private wl copy (lane writes row 'lane'; no barrier) ----
    __shared__ __align__(16) float wl[4][ROWS_PER_BLOCK * NCOL];
    {
        const float* rawl = ih ? v : u;
        const f32x4* rp = reinterpret_cast<const f32x4*>(rawl + (size_t)(rloc + lane) * NCOL);
        f32x4 l0 = rp[0], l1 = rp[1];
        l0.x *= inv[0]; l0.y *= inv[1]; l0.z *= inv[2]; l0.w *= inv[3];
        l1.x *= inv[4]; l1.y *= inv[5]; l1.z *= inv[6]; l1.w *= inv[7];
        f32x4* wp = reinterpret_cast<f32x4*>(&wl[wave][lane * NCOL]);
        wp[0] = l0; wp[1] = l1;
    }

    // ---- right fragment in registers ----
    const float* rawr = jh ? v : u;
    float wr[4][NCOL];
#pragma unroll
    for (int k = 0; k < 4; ++k) {
        const f32x4* p = reinterpret_cast<const f32x4*>(rawr + (size_t)(jloc + k) * NCOL);
        f32x4 a = p[0], bq = p[1];
        wr[k][0] = a.x * inv[0];  wr[k][1] = a.y * inv[1];
        wr[k][2] = a.z * inv[2];  wr[k][3] = a.w * inv[3];
        wr[k][4] = bq.x * inv[4]; wr[k][5] = bq.y * inv[5];
        wr[k][6] = bq.z * inv[6]; wr[k][7] = bq.w * inv[7];
    }

    // ---- prefetch slot 1 ----
#pragma unroll
    for (int k = 0; k < BR; ++k)
        buf[1][k] = nt_load(xrow0 + (size_t)(BR + k) * NALL);

    const float* wlw = &wl[wave][0];
    const int q = ih + 2 * jh;
    float acc[NCOL];
#pragma unroll
    for (int c = 0; c < NCOL; ++c) acc[c] = 0.f;

    // ---- main loop: 32 slots, double-buffered, fully unrolled ----
#pragma unroll
    for (int i = 0; i < NSLOT; ++i) {
        const int rb = (i & 15) * BR;            // row offset within chunk
        // consume slot i from buf[i&1]
#pragma unroll
        for (int k = 0; k < BR; ++k) {
            f32x4 xv = buf[i & 1][k];
            float t[NCOL];
#pragma unroll
            for (int c = 0; c < NCOL; ++c)
                t[c] = fmaf(xv.x, wr[0][c],
                       fmaf(xv.y, wr[1][c],
                       fmaf(xv.z, wr[2][c],
                            xv.w * wr[3][c])));
            const int row = rb + k;
            f32x4 wa = *reinterpret_cast<const f32x4*>(&wlw[row * NCOL]);
            f32x4 wb = *reinterpret_cast<const f32x4*>(&wlw[row * NCOL + 4]);
            acc[0] = fmaf(wa.x, t[0], acc[0]);
            acc[1] = fmaf(wa.y, t[1], acc[1]);
            acc[2] = fmaf(wa.z, t[2], acc[2]);
            acc[3] = fmaf(wa.w, t[3], acc[3]);
            acc[4] = fmaf(wb.x, t[4], acc[4]);
            acc[5] = fmaf(wb.y, t[5], acc[5]);
            acc[6] = fmaf(wb.z, t[6], acc[6]);
            acc[7] = fmaf(wb.w, t[7], acc[7]);
        }
        // issue slot i+2 into the buffer just freed
        if (i + 2 < NSLOT) {
            const int ns = i + 2;
            const float* nb = (ns < NSLOT / 2) ? xrow0 : xrow1;
            const int nrb = (ns & 15) * BR;
#pragma unroll
            for (int k = 0; k < BR; ++k)
                buf[i & 1][k] = nt_load(nb + (size_t)(nrb + k) * NALL);
        }
        // seam / end: reduce + atomic flush for the finished sample
        if (i == NSLOT / 2 - 1 || i == NSLOT - 1) {
            const int s = (i >= NSLOT / 2) ? 1 : 0;
#pragma unroll
            for (int c = 0; c < NCOL; ++c) {
#pragma unroll
                for (int off = 32; off >= 1; off >>= 1)
                    acc[c] += __shfl_xor(acc[c], off, 64);
            }
            if (lane == 0) {
                float* o = out + (size_t)(pair * SAMPLES + s) * (4 * NCOL) + q * NCOL;
#pragma unroll
                for (int c = 0; c < NCOL; ++c)
                    atomicAdd(o + c, acc[c]);
            }
#pragma unroll
            for (int c = 0; c < NCOL; ++c) acc[c] = 0.f;
        }
    }
}

extern "C" void kernel_launch(void* const* d_in, const int* in_sizes, int n_in,
                              void* d_out, int out_size, void* d_ws, size_t ws_size,
                              hipStream_t stream) {
    const float* x = (const float*)d_in[0];
    const float* u = (const float*)d_in[1];
    const float* v = (const float*)d_in[2];
    float* out = (float*)d_out;

    const int b_count = in_sizes[0] / (NALL * NALL);   // 128

    // zero the accumulated output every call (atomics accumulate into it)
    (void)hipMemsetAsync(d_out, 0, (size_t)out_size * sizeof(float), stream);

    dim3 grid((b_count / SAMPLES) * CHUNKS);   // 1024
    jxy_kernel<<<grid, THREADS, 0, stream>>>(x, u, v, out);
}